// Round 7
// baseline (203.053 us; speedup 1.0000x reference)
//
#include <hip/hip_runtime.h>
#include <stdint.h>

// LocalCorrelation on MI355X (gfx950).  R7 = R6 with 32-w nt blocks for occupancy.
// R6 post-mortem: nt latency-bound; VGPR stayed 52 (compiler sank the register-
// array loads), LDS 38.4 KB capped 4 blocks/CU = 50% occupancy, measured 30%,
// 1.9 TB/s. R7: nt block = 32 w-pixels -> LDS ~21.7 KB -> 7 blocks/CU (87%),
// grid 4096, 8 loads/thread. Banks: stride-17-dword rotation + XOR swizzle
// w^(4*(c>>5)) -> <=2-way both phases. corr unchanged from R5/R6 (passing).

typedef _Float16 half8 __attribute__((ext_vector_type(8)));
typedef _Float16 half2v __attribute__((ext_vector_type(2)));
typedef float floatx4 __attribute__((ext_vector_type(4)));

#define B_ 4
#define C_ 256
#define H_ 128
#define W_ 128
#define K2_ 169
#define INV_T 14.285714285714286f
#define KGS (H_ * W_ * 32)  // element stride between kg planes (per b)
#define TS 34               // nt tile row stride in halfs (17 dwords, odd)

static __device__ __forceinline__ void gload16(const void* g, void* l) {
  __builtin_amdgcn_global_load_lds((const __attribute__((address_space(1))) void*)g,
                                   (__attribute__((address_space(3))) void*)l, 16, 0, 0);
}

// ---------------- Pass 1: normalize + transpose (32-w blocks) ----------------
__global__ __launch_bounds__(256, 6) void nt_kernel(const float* __restrict__ fa,
                                                    const float* __restrict__ fb,
                                                    _Float16* __restrict__ an,
                                                    _Float16* __restrict__ bn) {
  __shared__ _Float16 tile[256 * TS];  // [c][32w + 2 pad], XOR-swizzled
  __shared__ float ps[32 * 32];        // [cp][w]
  __shared__ float invn[32];
  const int bid = blockIdx.x;
  const int wq = bid & 3, h = (bid >> 2) & 127, bb = (bid >> 9) & 3, tens = bid >> 11;
  const float* __restrict__ src = tens ? fb : fa;
  _Float16* __restrict__ dst = tens ? bn : an;
  const int t = threadIdx.x;
  const int f = t & 7, cp = t >> 3;  // w = wq*32 + f*4 ; c = it*32 + cp

  const float* gs = src + (((size_t)bb * C_ + cp) * H_ + h) * W_ + wq * 32 + f * 4;

  floatx4 v[8];
  #pragma unroll
  for (int it = 0; it < 8; ++it)
    v[it] = *(const floatx4*)(gs + (size_t)it * 32 * H_ * W_);

  floatx4 ss0 = {0.f, 0.f, 0.f, 0.f}, ss1 = {0.f, 0.f, 0.f, 0.f};
  #pragma unroll
  for (int it = 0; it < 8; ++it) {
    if (it & 1) ss1 += v[it] * v[it]; else ss0 += v[it] * v[it];
    const int c = it * 32 + cp;
    const int s = ((c >> 5) & 7) * 4;  // XOR swizzle on bits 2..4 of w
    _Float16* wp = tile + c * TS + ((f * 4) ^ s);
    half2v p0 = {(_Float16)v[it].x, (_Float16)v[it].y};
    half2v p1 = {(_Float16)v[it].z, (_Float16)v[it].w};
    *(half2v*)wp = p0;
    *(half2v*)(wp + 2) = p1;
  }
  const floatx4 ss = ss0 + ss1;
  *(floatx4*)(ps + cp * 32 + f * 4) = ss;
  __syncthreads();
  if (t < 32) {
    float s2 = 0.f;
    #pragma unroll
    for (int p = 0; p < 32; ++p) s2 += ps[p * 32 + t];
    invn[t] = 1.0f / fmaxf(sqrtf(s2), 1e-12f);
  }
  __syncthreads();

  // Phase 2: thread = (16-channel chunk cs = t>>4, pixel pair pr = t&15).
  const int cs = t >> 4, pr = t & 15;
  const int kg = cs >> 1, hc = cs & 1;   // kg plane, 16-channel half within kg
  const float sc = tens ? 1.0f : INV_T;  // fold 1/T into a
  const float inv0 = invn[2 * pr] * sc, inv1 = invn[2 * pr + 1] * sc;
  const int s = (cs >> 1) * 4;           // == swizzle of all c in this chunk
  const int ppr = (2 * pr) ^ s;
  _Float16 o0[16] __attribute__((aligned(16)));
  _Float16 o1[16] __attribute__((aligned(16)));
  #pragma unroll
  for (int j = 0; j < 16; ++j) {
    const int c = cs * 16 + j;
    const half2v d = *(const half2v*)(tile + c * TS + ppr);
    o0[j] = (_Float16)((float)d.x * inv0);
    o1[j] = (_Float16)((float)d.y * inv1);
  }
  _Float16* dp = dst + ((((size_t)bb * 8 + kg) * H_ + h) * W_ + wq * 32 + 2 * pr) * 32 + hc * 16;
  *(uint4*)(dp) = *(const uint4*)(o0);
  *(uint4*)(dp + 8) = *(const uint4*)(o0 + 8);
  *(uint4*)(dp + 32) = *(const uint4*)(o1);
  *(uint4*)(dp + 40) = *(const uint4*)(o1 + 8);
}

// ---------------- Pass 2: band-GEMM correlation (unchanged from R5) ----------------
// Per 32 KB buffer, LDS byte offset of job = job*16:
//   b-halo jobs [0, 28672): job = (row*28+col)*4+qt ; a jobs [28672, 32768).
// Frag reads (hw): A[r] at 14336 + (r*16+ml)*32 + q*8 ; B at jj*896 + col*32 + q*8.
union SmemU { _Float16 stage[2][16384]; float ostage[K2_ * 2 * 17]; };  // 64 KB

__global__ __launch_bounds__(512, 4) void corr_kernel(const _Float16* __restrict__ an,
                                                      const _Float16* __restrict__ bn,
                                                      float* __restrict__ out) {
  __shared__ SmemU u;
  const int bid = blockIdx.x;
  const int xcd = bid & 7, l = bid >> 3;  // XCD-contiguous h-bands
  const int bb = l >> 5, hseg = (l >> 3) & 3, wt = l & 7;
  const int hg = xcd * 4 + hseg;
  const int h0 = hg * 4, w0 = wt * 16;
  const int t = threadIdx.x;
  const int lane = t & 63, wv = t >> 6;  // 8 waves
  const int ml = lane & 15, q = lane >> 4;
  const int ntile = wv & 1, jjg = wv >> 1;

  const _Float16* ptr[4];
  unsigned flags = 0u;
  #pragma unroll
  for (int j = 0; j < 4; ++j) {
    const int job = j * 512 + t;
    if (job < 1792) {  // b-halo: 16 rows x 28 cols x 4 quarters
      const int row = job / 112, rem = job - row * 112;
      const int col = rem >> 2, qt = rem & 3;
      const int rim = h0 - 6 + row, cim = w0 - 6 + col;
      const bool ok = ((unsigned)rim < (unsigned)H_) && ((unsigned)cim < (unsigned)W_);
      ptr[j] = bn + (((size_t)bb * 8 * H_ + (ok ? rim : 0)) * W_ + (ok ? cim : 0)) * 32 + qt * 8;
      if (ok) flags |= 1u << j;
    } else {           // a-tile: 64 px (r*16+m) x 4 quarters
      const int aj = job - 1792;
      const int px = aj >> 2, qt = aj & 3;
      const int r = px >> 4, m = px & 15;
      ptr[j] = an + (((size_t)bb * 8 * H_ + h0 + r) * W_ + w0 + m) * 32 + qt * 8;
      flags |= 1u << j;
    }
  }

  const uint4 z4 = make_uint4(0u, 0u, 0u, 0u);
  #pragma unroll
  for (int j = 0; j < 4; ++j) {
    *(uint4*)((char*)u.stage[0] + (j * 512 + t) * 16) = z4;
    *(uint4*)((char*)u.stage[1] + (j * 512 + t) * 16) = z4;
  }
  __syncthreads();

  #pragma unroll
  for (int j = 0; j < 4; ++j) {
    if (flags & (1u << j))
      gload16(ptr[j], (char*)u.stage[0] + (j * 512 + wv * 64) * 16);
    ptr[j] += KGS;
  }

  floatx4 acc[4][4] = {};  // [uu: jj=jjg+4uu][r]; 13 of 16 valid per wave

  for (int kg = 0; kg < 8; ++kg) {
    __syncthreads();  // drains kg's DMA; all kg-1 frag reads already complete
    if (kg < 7) {
      char* nb = (char*)u.stage[(kg + 1) & 1];
      #pragma unroll
      for (int j = 0; j < 4; ++j) {
        if (flags & (1u << j))
          gload16(ptr[j], nb + (j * 512 + wv * 64) * 16);
        ptr[j] += KGS;
      }
    }
    const _Float16* sb = u.stage[kg & 1];

    half8 A[4];
    #pragma unroll
    for (int r = 0; r < 4; ++r)
      A[r] = *(const half8*)(sb + 14336 + (r * 16 + ml) * 32 + q * 8);

    #pragma unroll
    for (int uu = 0; uu < 4; ++uu) {
      const int jj = jjg + 4 * uu;
      const half8 Bf = *(const half8*)(sb + jj * 896 + (ntile * 16 + ml) * 32 + q * 8);
      #pragma unroll
      for (int r = 0; r < 4; ++r) {
        if ((uu == 0 && r > jjg) || (uu == 3 && r < jjg)) continue;  // dy out of band
        acc[uu][r] = __builtin_amdgcn_mfma_f32_16x16x32_f16(A[r], Bf, acc[uu][r], 0, 0, 0);
      }
    }
  }

  // ---- epilogue: 2 rounds of 2 rows; ostage (22984 B) overlays buf0 only ----
  #pragma unroll
  for (int r2 = 0; r2 < 2; ++r2) {
    if (r2) __syncthreads();
    #pragma unroll
    for (int uu = 0; uu < 4; ++uu) {
      const int jj = jjg + 4 * uu;
      const int col = ntile * 16 + ml;
      #pragma unroll
      for (int rr = 2 * r2; rr < 2 * r2 + 2; ++rr) {
        if ((uu == 0 && rr > jjg) || (uu == 3 && rr < jjg)) continue;
        const int dy6 = jj - rr;  // in [0,12]
        #pragma unroll
        for (int p = 0; p < 4; ++p) {
          const int ip = q * 4 + p;
          const int dx6 = col - ip;
          if (dx6 >= 0 && dx6 <= 12)
            u.ostage[((dy6 * 13 + dx6) * 2 + (rr & 1)) * 17 + ip] = acc[uu][rr][p];
        }
      }
    }
    __syncthreads();
    for (int s = t; s < K2_ * 32; s += 512) {
      const int k = s >> 5, r1 = (s >> 4) & 1, ip = s & 15;
      out[(((size_t)bb * K2_ + k) * H_ + h0 + 2 * r2 + r1) * W_ + w0 + ip] =
          u.ostage[(k * 2 + r1) * 17 + ip];
    }
  }
}

extern "C" void kernel_launch(void* const* d_in, const int* in_sizes, int n_in,
                              void* d_out, int out_size, void* d_ws, size_t ws_size,
                              hipStream_t stream) {
  const float* fa = (const float*)d_in[0];
  const float* fb = (const float*)d_in[1];
  float* out = (float*)d_out;
  _Float16* an = (_Float16*)d_ws;                 // 33.55 MB, [b][kg][h][w][32]
  _Float16* bn = an + (size_t)B_ * H_ * W_ * C_;  // 33.55 MB
  nt_kernel<<<4096, 256, 0, stream>>>(fa, fb, an, bn);
  corr_kernel<<<1024, 512, 0, stream>>>(an, bn, out);
}